// Round 1
// baseline (244.311 us; speedup 1.0000x reference)
//
#include <hip/hip_runtime.h>
#include <math.h>

#define BB 16
#define NN 65536
#define DD 24
#define KK 512
#define CH 64              // chunks (blocks) per batch for k1/k3
#define HPB (NN / CH)      // 1024 hits per block
#define TPB 256
#define RPB 4              // rows per block in repulsion
#define GB (KK / RPB)      // 128 repulsion blocks per batch

__device__ __forceinline__ float fixnum(float v) {
  return __builtin_isfinite(v) ? v : 0.0f;  // nan_to_num(nan=0, posinf=0, neginf=0)
}

// Full-block sum; returns total in ALL threads. sbuf must hold >= 4 floats.
__device__ __forceinline__ float blockReduceSum(float v, float* sbuf) {
  __syncthreads();                       // protect sbuf reuse across calls
  #pragma unroll
  for (int off = 32; off > 0; off >>= 1) v += __shfl_down(v, off, 64);
  int wid = threadIdx.x >> 6, lane = threadIdx.x & 63;
  if (lane == 0) sbuf[wid] = v;
  __syncthreads();
  return sbuf[0] + sbuf[1] + sbuf[2] + sbuf[3];
}

// ---- K1: per-hit segment stats (count, softmax denom, cp stats, margin) ----
__global__ __launch_bounds__(TPB) void k1_seg(
    const float* __restrict__ beta, const int* __restrict__ sid,
    const int* __restrict__ iscp,
    float* __restrict__ cnt_part, float* __restrict__ den_part,
    float* __restrict__ cp_cnt, float* __restrict__ cp_logit,
    int* __restrict__ first_cp, float* __restrict__ margin)
{
  __shared__ float s_cnt[KK];
  __shared__ float s_den[KK];
  __shared__ float sred[4];
  int b = blockIdx.x / CH, c = blockIdx.x % CH, t = threadIdx.x;
  for (int k = t; k < KK; k += TPB) { s_cnt[k] = 0.f; s_den[k] = 0.f; }
  __syncthreads();
  float pm = 0.f, nm = 0.f;
  #pragma unroll
  for (int i = 0; i < HPB / TPB; ++i) {
    int h = c * HPB + i * TPB + t;          // index within batch
    size_t g = (size_t)b * NN + h;
    float bv = fixnum(beta[g]);
    float bc = fminf(fmaxf(bv, -20.f), 20.f);
    float logit = bc / 0.7f;                // TAU
    int s = sid[g];
    atomicAdd(&s_cnt[s], 1.0f);
    atomicAdd(&s_den[s], expf(logit));      // max-free denom (no overflow: <=1.7e17)
    float prob = 1.0f / (1.0f + expf(-bc));
    if (iscp[g] == 1) {
      atomicAdd(&cp_cnt[b * KK + s], 1.0f);
      atomicAdd(&cp_logit[b * KK + s], logit);
      atomicMin(&first_cp[b * KK + s], h);
      pm += fmaxf(0.7f - prob, 0.f);        // THRESHOLD+MARGIN
    } else {
      nm += fmaxf(prob - 0.3f, 0.f);        // THRESHOLD-MARGIN
    }
  }
  float pms = blockReduceSum(pm, sred);
  float nms = blockReduceSum(nm, sred);
  if (t == 0) { atomicAdd(&margin[2 * b], pms); atomicAdd(&margin[2 * b + 1], nms); }
  __syncthreads();
  for (int k = t; k < KK; k += TPB) {
    cnt_part[((size_t)b * CH + c) * KK + k] = s_cnt[k];
    den_part[((size_t)b * CH + c) * KK + k] = s_den[k];
  }
}

// ---- K2: per-(b,k) finalize segments + gather cp_emb ----
__global__ __launch_bounds__(TPB) void k2_fin(
    const float* __restrict__ embed,
    const float* __restrict__ cnt_part, const float* __restrict__ den_part,
    const float* __restrict__ cp_cnt, const float* __restrict__ cp_logit,
    const int* __restrict__ first_cp,
    float* __restrict__ seg_cnt, float* __restrict__ loss_v,
    float* __restrict__ valid_f, float* __restrict__ has_cp_f,
    float* __restrict__ cp_emb)
{
  int idx = blockIdx.x * TPB + threadIdx.x;
  if (idx >= BB * KK) return;
  int b = idx / KK, k = idx - b * KK;
  float cnt = 0.f, den = 0.f;
  for (int c = 0; c < CH; ++c) {
    cnt += cnt_part[((size_t)b * CH + c) * KK + k];
    den += den_part[((size_t)b * CH + c) * KK + k];
  }
  bool present = cnt > 0.f;
  bool vinst = present && (cp_cnt[idx] == 1.0f);
  float p = expf(cp_logit[idx]) / fmaxf(den, 1e-30f);
  float loss = -logf(p + 1e-9f);
  loss_v[idx] = vinst ? loss : 0.f;
  valid_f[idx] = vinst ? 1.f : 0.f;
  int fc = first_cp[idx];                 // 0x7f7f7f7f if no cp hit
  has_cp_f[idx] = ((fc < NN) && present) ? 1.f : 0.f;
  seg_cnt[idx] = cnt;
  int row = fc < NN ? fc : NN - 1;        // min(first_cp, n-1)
  const float4* src = (const float4*)(embed + ((size_t)b * NN + row) * DD);
  float4* dst = (float4*)(cp_emb + (size_t)idx * DD);
  #pragma unroll
  for (int q = 0; q < DD / 4; ++q) {
    float4 v = src[q];
    v.x = fixnum(v.x); v.y = fixnum(v.y); v.z = fixnum(v.z); v.w = fixnum(v.w);
    dst[q] = v;
  }
}

// ---- K3: attraction — the big embed pass ----
__global__ __launch_bounds__(TPB) void k3_attr(
    const float* __restrict__ embed, const int* __restrict__ sid,
    const float* __restrict__ cp_emb, float* __restrict__ d2_part)
{
  __shared__ float s_ce[KK * DD];   // 48 KiB: cp_emb for this batch
  __shared__ float s_d2[KK];
  int b = blockIdx.x / CH, c = blockIdx.x % CH, t = threadIdx.x;
  const float4* src = (const float4*)(cp_emb + (size_t)b * KK * DD);
  float4* dst = (float4*)s_ce;
  for (int i = t; i < KK * DD / 4; i += TPB) dst[i] = src[i];
  for (int k = t; k < KK; k += TPB) s_d2[k] = 0.f;
  __syncthreads();
  #pragma unroll
  for (int i = 0; i < HPB / TPB; ++i) {
    int h = c * HPB + i * TPB + t;
    size_t g = (size_t)b * NN + h;
    const float4* e = (const float4*)(embed + g * DD);  // 96B rows, 16B aligned
    int s = sid[g];
    const float4* ce = (const float4*)(s_ce + s * DD);
    float d2 = 0.f;
    #pragma unroll
    for (int q = 0; q < DD / 4; ++q) {
      float4 ev = e[q]; float4 cv = ce[q];
      float x;
      x = fixnum(ev.x) - cv.x; d2 += x * x;
      x = fixnum(ev.y) - cv.y; d2 += x * x;
      x = fixnum(ev.z) - cv.z; d2 += x * x;
      x = fixnum(ev.w) - cv.w; d2 += x * x;
    }
    atomicAdd(&s_d2[s], fminf(d2, 50.f));
  }
  __syncthreads();
  for (int k = t; k < KK; k += TPB)
    d2_part[((size_t)b * CH + c) * KK + k] = s_d2[k];
}

// ---- K3b: repulsion (incl. diagonal), register-blocked ----
__global__ __launch_bounds__(TPB) void k3b_rep(
    const float* __restrict__ cp_emb, const float* __restrict__ has_cp_f,
    float* __restrict__ rep_sum)
{
  __shared__ float sred[4];
  int b = blockIdx.x / GB;
  int r0 = (blockIdx.x % GB) * RPB;
  int t = threadIdx.x;
  int j0 = t, j1 = t + TPB;
  const float* base = cp_emb + (size_t)b * KK * DD;
  float cj0[DD], cj1[DD];
  #pragma unroll
  for (int d = 0; d < DD; ++d) { cj0[d] = base[j0 * DD + d]; cj1[d] = base[j1 * DD + d]; }
  float m0 = has_cp_f[b * KK + j0], m1 = has_cp_f[b * KK + j1];
  float acc = 0.f;
  for (int ri = 0; ri < RPB; ++ri) {
    int i = r0 + ri;
    float mi = has_cp_f[b * KK + i];      // uniform -> scalar load
    float d20 = 0.f, d21 = 0.f;
    #pragma unroll
    for (int d = 0; d < DD; ++d) {
      float ci = base[i * DD + d];        // uniform -> scalar load
      float x0 = ci - cj0[d]; d20 += x0 * x0;
      float x1 = ci - cj1[d]; d21 += x1 * x1;
    }
    acc += mi * (m0 * expf(-fminf(d20, 50.f)) + m1 * expf(-fminf(d21, 50.f)));
  }
  float tot = blockReduceSum(acc, sred);
  if (t == 0) atomicAdd(&rep_sum[b], tot);
}

// ---- K4: per-batch finalize ----
__global__ __launch_bounds__(TPB) void k4_batch(
    const float* __restrict__ d2_part, const float* __restrict__ seg_cnt,
    const float* __restrict__ loss_v, const float* __restrict__ valid_f,
    const float* __restrict__ cp_cnt, const float* __restrict__ has_cp_f,
    const float* __restrict__ margin, const float* __restrict__ rep_sum,
    float* __restrict__ batch_out)
{
  __shared__ float sred[4];
  int b = blockIdx.x, t = threadIdx.x;
  float attr = 0.f, ce = 0.f, vcnt = 0.f, pcnt = 0.f, mcnt = 0.f;
  for (int k = t; k < KK; k += TPB) {
    float ds = 0.f;
    for (int c = 0; c < CH; ++c) ds += d2_part[((size_t)b * CH + c) * KK + k];
    int idx = b * KK + k;
    float cnt = seg_cnt[idx];
    float hc = has_cp_f[idx];
    attr += hc * (ds / fmaxf(cnt, 1.f));
    ce += loss_v[idx];
    vcnt += valid_f[idx];
    pcnt += cp_cnt[idx];
    mcnt += hc;
  }
  attr = blockReduceSum(attr, sred);
  ce   = blockReduceSum(ce, sred);
  vcnt = blockReduceSum(vcnt, sred);
  pcnt = blockReduceSum(pcnt, sred);
  mcnt = blockReduceSum(mcnt, sred);
  if (t == 0) {
    float pos = pcnt, neg = (float)NN - pos;
    float slice_ce = ce / fmaxf(vcnt, 1.f);
    float pm = margin[2 * b] / fmaxf(pos, 1.f);
    float nm = margin[2 * b + 1] / fmaxf(neg, 1.f);
    float beta_loss = slice_ce + 5.0f * (pm + nm);   // MARGIN_WEIGHT
    float rep = rep_sum[b] / fmaxf(mcnt * mcnt, 1.f);
    float repulsion = (mcnt > 1.f) ? 1.5f * rep : 0.f;  // REPULSION_WEIGHT
    float valid = (pos >= 1.f && neg >= 1.f && vcnt > 0.f) ? 1.f : 0.f;
    batch_out[b * 8 + 0] = beta_loss + attr + repulsion;
    batch_out[b * 8 + 1] = beta_loss;
    batch_out[b * 8 + 2] = attr;
    batch_out[b * 8 + 3] = repulsion;
    batch_out[b * 8 + 4] = valid;
  }
}

// ---- K5: batch average ----
__global__ void k5_final(const float* __restrict__ batch_out, float* __restrict__ out) {
  if (threadIdx.x == 0 && blockIdx.x == 0) {
    float s0 = 0.f, s1 = 0.f, s2 = 0.f, s3 = 0.f, c = 0.f;
    for (int b = 0; b < BB; ++b) {
      float v = batch_out[b * 8 + 4];
      c  += v;
      s0 += batch_out[b * 8 + 0] * v;
      s1 += batch_out[b * 8 + 1] * v;
      s2 += batch_out[b * 8 + 2] * v;
      s3 += batch_out[b * 8 + 3] * v;
    }
    float safe = fmaxf(c, 1.f);
    bool ok = c > 0.f;
    out[0] = ok ? s0 / safe : 0.f;
    out[1] = ok ? s1 / safe : 0.f;
    out[2] = ok ? s2 / safe : 0.f;
    out[3] = ok ? s3 / safe : 0.f;
  }
}

extern "C" void kernel_launch(void* const* d_in, const int* in_sizes, int n_in,
                              void* d_out, int out_size, void* d_ws, size_t ws_size,
                              hipStream_t stream) {
  (void)in_sizes; (void)n_in; (void)out_size; (void)ws_size;
  const float* beta  = (const float*)d_in[0];
  const float* embed = (const float*)d_in[1];
  const int*   sid   = (const int*)d_in[2];
  const int*   iscp  = (const int*)d_in[3];
  float* out = (float*)d_out;
  char* ws = (char*)d_ws;

  size_t off = 0;
  auto alloc = [&](size_t bytes) {
    size_t o = off; off += (bytes + 255) & ~(size_t)255; return o;
  };
  const size_t BKf = (size_t)BB * KK * 4;
  size_t o_cp_cnt  = alloc(BKf);                      // zero
  size_t o_cp_lg   = alloc(BKf);                      // zero
  size_t o_margin  = alloc((size_t)BB * 2 * 4);       // zero
  size_t o_rep     = alloc((size_t)BB * 4);           // zero
  size_t zero_end  = off;
  size_t o_first   = alloc(BKf);                      // 0x7f (== +inf for atomicMin)
  size_t o_cnt_p   = alloc((size_t)BB * CH * KK * 4);
  size_t o_den_p   = alloc((size_t)BB * CH * KK * 4);
  size_t o_d2_p    = alloc((size_t)BB * CH * KK * 4);
  size_t o_cpe     = alloc((size_t)BB * KK * DD * 4);
  size_t o_segc    = alloc(BKf);
  size_t o_lossv   = alloc(BKf);
  size_t o_validf  = alloc(BKf);
  size_t o_hascp   = alloc(BKf);
  size_t o_bout    = alloc((size_t)BB * 8 * 4);

  hipMemsetAsync(ws, 0, zero_end, stream);
  hipMemsetAsync(ws + o_first, 0x7f, BKf, stream);

  k1_seg<<<BB * CH, TPB, 0, stream>>>(beta, sid, iscp,
      (float*)(ws + o_cnt_p), (float*)(ws + o_den_p),
      (float*)(ws + o_cp_cnt), (float*)(ws + o_cp_lg),
      (int*)(ws + o_first), (float*)(ws + o_margin));

  k2_fin<<<(BB * KK) / TPB, TPB, 0, stream>>>(embed,
      (const float*)(ws + o_cnt_p), (const float*)(ws + o_den_p),
      (const float*)(ws + o_cp_cnt), (const float*)(ws + o_cp_lg),
      (const int*)(ws + o_first),
      (float*)(ws + o_segc), (float*)(ws + o_lossv), (float*)(ws + o_validf),
      (float*)(ws + o_hascp), (float*)(ws + o_cpe));

  k3_attr<<<BB * CH, TPB, 0, stream>>>(embed, sid,
      (const float*)(ws + o_cpe), (float*)(ws + o_d2_p));

  k3b_rep<<<BB * GB, TPB, 0, stream>>>((const float*)(ws + o_cpe),
      (const float*)(ws + o_hascp), (float*)(ws + o_rep));

  k4_batch<<<BB, TPB, 0, stream>>>((const float*)(ws + o_d2_p),
      (const float*)(ws + o_segc), (const float*)(ws + o_lossv),
      (const float*)(ws + o_validf), (const float*)(ws + o_cp_cnt),
      (const float*)(ws + o_hascp), (const float*)(ws + o_margin),
      (const float*)(ws + o_rep), (float*)(ws + o_bout));

  k5_final<<<1, 64, 0, stream>>>((const float*)(ws + o_bout), out);
}

// Round 2
// 200.328 us; speedup vs baseline: 1.2196x; 1.2196x over previous
//
#include <hip/hip_runtime.h>
#include <math.h>

#define BB 16
#define NN 65536
#define DD 24
#define KK 512
#define CH 64              // chunks (blocks) per batch for k1/k3
#define HPB (NN / CH)      // 1024 hits per block-chunk
#define TPB 256
#define RPB 8              // repulsion rows per block (CH*RPB == KK)

__device__ __forceinline__ float fixnum(float v) {
  return __builtin_isfinite(v) ? v : 0.0f;  // nan_to_num(nan=0, posinf=0, neginf=0)
}

// Full-block (256-thread) sum; returns total in ALL threads.
__device__ __forceinline__ float blockReduceSum(float v, float* sbuf) {
  __syncthreads();
  #pragma unroll
  for (int off = 32; off > 0; off >>= 1) v += __shfl_down(v, off, 64);
  int wid = threadIdx.x >> 6, lane = threadIdx.x & 63;
  if (lane == 0) sbuf[wid] = v;
  __syncthreads();
  return sbuf[0] + sbuf[1] + sbuf[2] + sbuf[3];
}

// ---- K1: per-hit scan -> LDS segment partials (no global atomics, no init) ----
__global__ __launch_bounds__(TPB) void k1_seg(
    const float* __restrict__ beta, const int* __restrict__ sid,
    const int* __restrict__ iscp,
    float* __restrict__ cnt_p, float* __restrict__ den_p,
    float* __restrict__ cpc_p, float* __restrict__ cpl_p,
    int* __restrict__ first_p, float* __restrict__ marg_p)
{
  __shared__ float s_cnt[KK], s_den[KK], s_cpc[KK], s_cpl[KK];
  __shared__ int   s_first[KK];
  __shared__ float sred[4];
  int b = blockIdx.x >> 6, c = blockIdx.x & 63, t = threadIdx.x;
  for (int k = t; k < KK; k += TPB) {
    s_cnt[k] = 0.f; s_den[k] = 0.f; s_cpc[k] = 0.f; s_cpl[k] = 0.f; s_first[k] = NN;
  }
  __syncthreads();
  int h0 = c * HPB + t * 4;                 // 4 consecutive hits per thread
  size_t g0 = (size_t)b * NN + h0;
  float4 bv = *(const float4*)(beta + g0);
  int4   sv = *(const int4*)(sid + g0);
  int4   cv = *(const int4*)(iscp + g0);
  float pm = 0.f, nm = 0.f;
  float bs[4] = {bv.x, bv.y, bv.z, bv.w};
  int   ss[4] = {sv.x, sv.y, sv.z, sv.w};
  int   cs[4] = {cv.x, cv.y, cv.z, cv.w};
  #pragma unroll
  for (int j = 0; j < 4; ++j) {
    float bc = fminf(fmaxf(fixnum(bs[j]), -20.f), 20.f);
    float logit = bc * (1.0f / 0.7f);       // TAU
    int s = ss[j];
    atomicAdd(&s_cnt[s], 1.0f);
    atomicAdd(&s_den[s], __expf(logit));    // max-free denom (<=1.7e17, no overflow)
    float prob = 1.0f / (1.0f + __expf(-bc));
    if (cs[j] == 1) {
      atomicAdd(&s_cpc[s], 1.0f);
      atomicAdd(&s_cpl[s], logit);
      atomicMin(&s_first[s], h0 + j);
      pm += fmaxf(0.7f - prob, 0.f);        // THRESHOLD+MARGIN
    } else {
      nm += fmaxf(prob - 0.3f, 0.f);        // THRESHOLD-MARGIN
    }
  }
  float pms = blockReduceSum(pm, sred);
  float nms = blockReduceSum(nm, sred);
  if (t == 0) { marg_p[2 * blockIdx.x] = pms; marg_p[2 * blockIdx.x + 1] = nms; }
  __syncthreads();
  size_t base = ((size_t)b * CH + c) * KK;
  for (int k = t; k < KK; k += TPB) {
    cnt_p[base + k] = s_cnt[k]; den_p[base + k] = s_den[k];
    cpc_p[base + k] = s_cpc[k]; cpl_p[base + k] = s_cpl[k];
    first_p[base + k] = s_first[k];
  }
}

// ---- K2: reduce partials per (b,k); gather cp_emb; zero accumulators ----
__global__ __launch_bounds__(TPB) void k2_fin(
    const float* __restrict__ embed,
    const float* __restrict__ cnt_p, const float* __restrict__ den_p,
    const float* __restrict__ cpc_p, const float* __restrict__ cpl_p,
    const int* __restrict__ first_p,
    float* __restrict__ seg_cnt, float* __restrict__ loss_v,
    float* __restrict__ valid_f, float* __restrict__ has_cp_f,
    float* __restrict__ cpc_tot, float* __restrict__ cp_emb,
    float* __restrict__ d2_acc, float* __restrict__ rep_acc)
{
  int idx = blockIdx.x * TPB + threadIdx.x;   // 0 .. BB*KK-1
  int b = idx >> 9, k = idx & (KK - 1);
  float cnt = 0.f, den = 0.f, cpc = 0.f, cpl = 0.f;
  int fc = NN;
  #pragma unroll 8
  for (int c = 0; c < CH; ++c) {
    size_t base = ((size_t)b * CH + c) * KK + k;
    cnt += cnt_p[base]; den += den_p[base];
    cpc += cpc_p[base]; cpl += cpl_p[base];
    fc = min(fc, first_p[base]);
  }
  bool present = cnt > 0.f;
  bool vinst = present && (cpc == 1.0f);
  float p = __expf(cpl) / fmaxf(den, 1e-30f);
  seg_cnt[idx] = cnt;
  cpc_tot[idx] = cpc;
  loss_v[idx] = vinst ? -__logf(p + 1e-9f) : 0.f;
  valid_f[idx] = vinst ? 1.f : 0.f;
  has_cp_f[idx] = ((fc < NN) && present) ? 1.f : 0.f;
  d2_acc[idx] = 0.f;
  if (idx < BB) rep_acc[idx] = 0.f;
  int row = fc < NN ? fc : NN - 1;
  const float4* src = (const float4*)(embed + ((size_t)b * NN + row) * DD);
  float4* dst = (float4*)(cp_emb + (size_t)idx * DD);
  #pragma unroll
  for (int q = 0; q < DD / 4; ++q) {
    float4 v = src[q];
    v.x = fixnum(v.x); v.y = fixnum(v.y); v.z = fixnum(v.z); v.w = fixnum(v.w);
    dst[q] = v;
  }
}

// ---- K3: attraction scan (embed 100 MB pass) + fused repulsion ----
__global__ __launch_bounds__(TPB) void k3_attr_rep(
    const float* __restrict__ embed, const int* __restrict__ sid,
    const float* __restrict__ cp_emb, const float* __restrict__ has_cp_f,
    float* __restrict__ d2_acc, float* __restrict__ rep_acc)
{
  __shared__ float s_d2[KK];
  __shared__ float sred[4];
  int b = blockIdx.x >> 6, c = blockIdx.x & 63, t = threadIdx.x;
  for (int k = t; k < KK; k += TPB) s_d2[k] = 0.f;
  __syncthreads();
  const float* cebase = cp_emb + (size_t)b * KK * DD;
  #pragma unroll
  for (int i = 0; i < HPB / TPB; ++i) {
    int h = c * HPB + i * TPB + t;
    size_t g = (size_t)b * NN + h;
    int s = sid[g];
    const float4* e  = (const float4*)(embed + g * DD);
    const float4* ce = (const float4*)(cebase + (size_t)s * DD);  // L1/L2-hot gather
    float d2 = 0.f;
    #pragma unroll
    for (int q = 0; q < DD / 4; ++q) {
      float4 ev = e[q]; float4 cv = ce[q];
      float x;
      x = fixnum(ev.x) - cv.x; d2 += x * x;
      x = fixnum(ev.y) - cv.y; d2 += x * x;
      x = fixnum(ev.z) - cv.z; d2 += x * x;
      x = fixnum(ev.w) - cv.w; d2 += x * x;
    }
    atomicAdd(&s_d2[s], fminf(d2, 50.f));
  }
  __syncthreads();
  for (int k = t; k < KK; k += TPB)
    atomicAdd(&d2_acc[b * KK + k], s_d2[k]);   // 64 adds/address device-wide

  // --- repulsion: rows c*RPB..+RPB, cols j0=t, j1=t+TPB ---
  int j0 = t, j1 = t + TPB;
  float cj0[DD], cj1[DD];
  const float4* cj0p = (const float4*)(cebase + (size_t)j0 * DD);
  const float4* cj1p = (const float4*)(cebase + (size_t)j1 * DD);
  #pragma unroll
  for (int q = 0; q < DD / 4; ++q) {
    float4 a = cj0p[q], bq = cj1p[q];
    cj0[q*4] = a.x; cj0[q*4+1] = a.y; cj0[q*4+2] = a.z; cj0[q*4+3] = a.w;
    cj1[q*4] = bq.x; cj1[q*4+1] = bq.y; cj1[q*4+2] = bq.z; cj1[q*4+3] = bq.w;
  }
  float m0 = has_cp_f[b * KK + j0], m1 = has_cp_f[b * KK + j1];
  float acc = 0.f;
  #pragma unroll
  for (int ri = 0; ri < RPB; ++ri) {
    int i = c * RPB + ri;
    float mi = has_cp_f[b * KK + i];          // uniform
    float d20 = 0.f, d21 = 0.f;
    #pragma unroll
    for (int d = 0; d < DD; ++d) {
      float ci = cebase[i * DD + d];          // uniform -> broadcast
      float x0 = ci - cj0[d]; d20 += x0 * x0;
      float x1 = ci - cj1[d]; d21 += x1 * x1;
    }
    acc += mi * (m0 * __expf(-fminf(d20, 50.f)) + m1 * __expf(-fminf(d21, 50.f)));
  }
  float tot = blockReduceSum(acc, sred);
  if (t == 0) atomicAdd(&rep_acc[b], tot);
}

// ---- K4: one block; wave w = batch w; thread 0 combines ----
__global__ __launch_bounds__(1024) void k4_final(
    const float* __restrict__ d2_acc, const float* __restrict__ seg_cnt,
    const float* __restrict__ loss_v, const float* __restrict__ valid_f,
    const float* __restrict__ cpc_tot, const float* __restrict__ has_cp_f,
    const float* __restrict__ marg_p, const float* __restrict__ rep_acc,
    float* __restrict__ out)
{
  __shared__ float s_b[BB][5];
  int w = threadIdx.x >> 6, l = threadIdx.x & 63;   // wave w -> batch w
  int b = w;
  float attr = 0.f, ce = 0.f, vcnt = 0.f, pcnt = 0.f, mcnt = 0.f;
  #pragma unroll
  for (int k = l; k < KK; k += 64) {
    int idx = b * KK + k;
    float hc = has_cp_f[idx];
    attr += hc * (d2_acc[idx] / fmaxf(seg_cnt[idx], 1.f));
    ce   += loss_v[idx];
    vcnt += valid_f[idx];
    pcnt += cpc_tot[idx];
    mcnt += hc;
  }
  float pm = marg_p[(b * CH + l) * 2];      // 64 chunks == 64 lanes
  float nm = marg_p[(b * CH + l) * 2 + 1];
  #pragma unroll
  for (int off = 32; off > 0; off >>= 1) {
    attr += __shfl_down(attr, off, 64);
    ce   += __shfl_down(ce, off, 64);
    vcnt += __shfl_down(vcnt, off, 64);
    pcnt += __shfl_down(pcnt, off, 64);
    mcnt += __shfl_down(mcnt, off, 64);
    pm   += __shfl_down(pm, off, 64);
    nm   += __shfl_down(nm, off, 64);
  }
  if (l == 0) {
    float pos = pcnt, neg = (float)NN - pos;
    float slice_ce = ce / fmaxf(vcnt, 1.f);
    float beta_loss = slice_ce + 5.0f * (pm / fmaxf(pos, 1.f) + nm / fmaxf(neg, 1.f));
    float rep = rep_acc[b] / fmaxf(mcnt * mcnt, 1.f);
    float repulsion = (mcnt > 1.f) ? 1.5f * rep : 0.f;
    float v = (pos >= 1.f && neg >= 1.f && vcnt > 0.f) ? 1.f : 0.f;
    s_b[w][0] = (beta_loss + attr + repulsion) * v;
    s_b[w][1] = beta_loss * v;
    s_b[w][2] = attr * v;
    s_b[w][3] = repulsion * v;
    s_b[w][4] = v;
  }
  __syncthreads();
  if (threadIdx.x == 0) {
    float s0 = 0.f, s1 = 0.f, s2 = 0.f, s3 = 0.f, cv = 0.f;
    #pragma unroll
    for (int i = 0; i < BB; ++i) {
      s0 += s_b[i][0]; s1 += s_b[i][1]; s2 += s_b[i][2]; s3 += s_b[i][3]; cv += s_b[i][4];
    }
    float safe = fmaxf(cv, 1.f);
    bool ok = cv > 0.f;
    out[0] = ok ? s0 / safe : 0.f;
    out[1] = ok ? s1 / safe : 0.f;
    out[2] = ok ? s2 / safe : 0.f;
    out[3] = ok ? s3 / safe : 0.f;
  }
}

extern "C" void kernel_launch(void* const* d_in, const int* in_sizes, int n_in,
                              void* d_out, int out_size, void* d_ws, size_t ws_size,
                              hipStream_t stream) {
  (void)in_sizes; (void)n_in; (void)out_size; (void)ws_size;
  const float* beta  = (const float*)d_in[0];
  const float* embed = (const float*)d_in[1];
  const int*   sid   = (const int*)d_in[2];
  const int*   iscp  = (const int*)d_in[3];
  float* out = (float*)d_out;
  char* ws = (char*)d_ws;

  size_t off = 0;
  auto alloc = [&](size_t bytes) {
    size_t o = off; off += (bytes + 255) & ~(size_t)255; return o;
  };
  const size_t BCK = (size_t)BB * CH * KK * 4;   // 2 MB partial arrays
  const size_t BKf = (size_t)BB * KK * 4;        // 32 KB
  size_t o_cnt_p  = alloc(BCK);
  size_t o_den_p  = alloc(BCK);
  size_t o_cpc_p  = alloc(BCK);
  size_t o_cpl_p  = alloc(BCK);
  size_t o_first  = alloc(BCK);
  size_t o_marg   = alloc((size_t)BB * CH * 2 * 4);
  size_t o_segc   = alloc(BKf);
  size_t o_lossv  = alloc(BKf);
  size_t o_validf = alloc(BKf);
  size_t o_hascp  = alloc(BKf);
  size_t o_cpct   = alloc(BKf);
  size_t o_d2     = alloc(BKf);
  size_t o_cpe    = alloc((size_t)BB * KK * DD * 4);
  size_t o_rep    = alloc((size_t)BB * 4);

  k1_seg<<<BB * CH, TPB, 0, stream>>>(beta, sid, iscp,
      (float*)(ws + o_cnt_p), (float*)(ws + o_den_p),
      (float*)(ws + o_cpc_p), (float*)(ws + o_cpl_p),
      (int*)(ws + o_first), (float*)(ws + o_marg));

  k2_fin<<<(BB * KK) / TPB, TPB, 0, stream>>>(embed,
      (const float*)(ws + o_cnt_p), (const float*)(ws + o_den_p),
      (const float*)(ws + o_cpc_p), (const float*)(ws + o_cpl_p),
      (const int*)(ws + o_first),
      (float*)(ws + o_segc), (float*)(ws + o_lossv), (float*)(ws + o_validf),
      (float*)(ws + o_hascp), (float*)(ws + o_cpct), (float*)(ws + o_cpe),
      (float*)(ws + o_d2), (float*)(ws + o_rep));

  k3_attr_rep<<<BB * CH, TPB, 0, stream>>>(embed, sid,
      (const float*)(ws + o_cpe), (const float*)(ws + o_hascp),
      (float*)(ws + o_d2), (float*)(ws + o_rep));

  k4_final<<<1, 1024, 0, stream>>>((const float*)(ws + o_d2),
      (const float*)(ws + o_segc), (const float*)(ws + o_lossv),
      (const float*)(ws + o_validf), (const float*)(ws + o_cpct),
      (const float*)(ws + o_hascp), (const float*)(ws + o_marg),
      (const float*)(ws + o_rep), out);
}